// Round 7
// baseline (250.339 us; speedup 1.0000x reference)
//
#include <hip/hip_runtime.h>
#include <math.h>

#define B_  64
#define L_  2048
#define DM  12
#define DI  24
#define DS  16
#define DC  4
#define DTR 1
#define T_  (B_ * L_)        // 131072 tokens
#define NCHUNK 32
#define CHUNK  64            // L_ / NCHUNK

// ---------------- ws layout (floats) — identical to rounds 5/6 (passed) ----
// delta : T*DI   3,145,728
// xi    : T*DI   3,145,728
// zs    : T*DI   3,145,728
// y     : T*DI   3,145,728   (gated scan output, t-major)
// Bm    : T*DS   2,097,152
// Cm    : T*DS   2,097,152
// P     : B*DI*NCHUNK*DS   786,432   \ aliased as xf (B*DM*L = 1,572,864)
// H     : B*DI*NCHUNK*DS   786,432   /  after scan2 completes
// H0    : B*DI*NCHUNK*DS   786,432
// part  : 1024

__device__ __forceinline__ float siluf(float v)  { return v / (1.0f + __expf(-v)); }
__device__ __forceinline__ float softplusf(float v) {
    if (v > 20.0f)  return v;
    if (v < -20.0f) return __expf(v);
    return __logf(1.0f + __expf(v));
}
__device__ __forceinline__ float geluf(float v) {
    return 0.5f * v * (1.0f + erff(v * 0.70710678118654752440f));
}
__device__ __forceinline__ float eluf(float v) { return v > 0.0f ? v : __expf(v) - 1.0f; }

// DPP lane-sum: 16-lane reduce = xor1 (0xB1), xor2 (0x4E), row_ror:4 (0x124), row_ror:8 (0x128)
// (chain validated on-HW in rounds 3/4: absmax 0.0)
#define DPP_ADD(p, ctrl) \
    (p) += __int_as_float(__builtin_amdgcn_update_dpp(0, __float_as_int(p), (ctrl), 0xF, 0xF, true))

// ============ K1: in_proj + depthwise causal conv + silu + x_proj + delta ============
__global__ __launch_bounds__(256) void k_proj(
    const float* __restrict__ x, const float* __restrict__ w_in,
    const float* __restrict__ conv_w, const float* __restrict__ conv_b,
    const float* __restrict__ xproj_w, const float* __restrict__ dt_w,
    const float* __restrict__ dt_b,
    float* __restrict__ xi_out, float* __restrict__ zs_out,
    float* __restrict__ delta_out, float* __restrict__ Bm_out,
    float* __restrict__ Cm_out)
{
    __shared__ float s_xi[256 + 3][DI + 1];
    const int tid = threadIdx.x;
    const int b   = blockIdx.x >> 3;
    const int l0  = (blockIdx.x & 7) << 8;
    const int l   = l0 + tid;
    const int t   = b * L_ + l;

    float xv[DM];
    *(float4*)&xv[0] = *(const float4*)&x[t * DM + 0];
    *(float4*)&xv[4] = *(const float4*)&x[t * DM + 4];
    *(float4*)&xv[8] = *(const float4*)&x[t * DM + 8];

#pragma unroll
    for (int e = 0; e < DI; ++e) {
        float acc = 0.0f;
#pragma unroll
        for (int d = 0; d < DM; ++d) acc += xv[d] * w_in[(DI + e) * DM + d];
        zs_out[t * DI + e] = siluf(acc);
    }
#pragma unroll
    for (int e = 0; e < DI; ++e) {
        float acc = 0.0f;
#pragma unroll
        for (int d = 0; d < DM; ++d) acc += xv[d] * w_in[e * DM + d];
        s_xi[tid + 3][e] = acc;
    }
    if (tid < 3) {
        const int lh = l0 - 3 + tid;
        if (lh < 0) {
            for (int e = 0; e < DI; ++e) s_xi[tid][e] = 0.0f;
        } else {
            const int th = b * L_ + lh;
            float xh[DM];
            for (int d = 0; d < DM; ++d) xh[d] = x[th * DM + d];
            for (int e = 0; e < DI; ++e) {
                float acc = 0.0f;
                for (int d = 0; d < DM; ++d) acc += xh[d] * w_in[e * DM + d];
                s_xi[tid][e] = acc;
            }
        }
    }
    __syncthreads();

    float xi[DI];
#pragma unroll
    for (int dch = 0; dch < DI; ++dch) {
        float acc = conv_b[dch];
#pragma unroll
        for (int k = 0; k < DC; ++k) acc += s_xi[tid + k][dch] * conv_w[dch * DC + k];
        xi[dch] = siluf(acc);
        xi_out[t * DI + dch] = xi[dch];
    }

    float dt = 0.0f;
#pragma unroll
    for (int d = 0; d < DI; ++d) dt += xi[d] * xproj_w[d];
#pragma unroll
    for (int e = 0; e < DS; ++e) {
        float accB = 0.0f, accC = 0.0f;
#pragma unroll
        for (int d = 0; d < DI; ++d) {
            accB += xi[d] * xproj_w[(1 + e) * DI + d];
            accC += xi[d] * xproj_w[(1 + DS + e) * DI + d];
        }
        Bm_out[t * DS + e] = accB;
        Cm_out[t * DS + e] = accC;
    }
#pragma unroll
    for (int d = 0; d < DI; ++d)
        delta_out[t * DI + d] = softplusf(dt * dt_w[d] + dt_b[d]);
}

// ============ S1: local chunk scan — thread = (b,c,d,n), 1 state per lane ============
// 384-thread block = one chunk's (d,n) set; grid = B*NCHUNK = 2048 blocks, 12288 waves
__global__ __launch_bounds__(384) void k_scan1(
    const float* __restrict__ delta, const float* __restrict__ xi,
    const float* __restrict__ Bm, const float* __restrict__ A_log,
    float* __restrict__ P, float* __restrict__ H)
{
    const int tid = threadIdx.x;          // d*16 + n
    const int d   = tid >> 4;
    const int n   = tid & 15;
    const int b   = blockIdx.x >> 5;
    const int c   = blockIdx.x & 31;
    const int t0  = b * L_ + c * CHUNK;

    const float An = -__expf(A_log[tid]);
    float h = 0.0f, prod = 1.0f;

    const float* pD = delta + (size_t)t0 * DI + d;
    const float* pX = xi    + (size_t)t0 * DI + d;
    const float* pB = Bm    + (size_t)t0 * DS + n;

#pragma unroll 4
    for (int i = 0; i < CHUNK; ++i) {
        const float del = pD[i * DI];
        const float u   = del * pX[i * DI];
        const float Bv  = pB[i * DS];
        const float a   = __expf(del * An);
        h = a * h + u * Bv;
        prod *= a;
    }
    const int u = ((b * DI + d) * NCHUNK + c) * DS + n;
    P[u] = prod;
    H[u] = h;
}

// ============ S2: combine chunk summaries (thread = (b,d,n)) ============
__global__ __launch_bounds__(256) void k_scan2(
    const float* __restrict__ P, const float* __restrict__ H, float* __restrict__ H0)
{
    const int idx  = blockIdx.x * 256 + threadIdx.x;  // 24576 = (b*DI+d)*16 + n
    const int n    = idx & 15;
    const int rest = idx >> 4;
    float Hc = 0.0f;
    const int base = rest * NCHUNK * DS + n;
    for (int c = 0; c < NCHUNK; ++c) {
        const int u = base + c * DS;
        H0[u] = Hc;
        Hc = P[u] * Hc + H[u];
    }
}

// ============ S3: replay with h0 + fused gate, 1 state/lane, DPP 16-lane reduce ============
__global__ __launch_bounds__(384) void k_scan3(
    const float* __restrict__ delta, const float* __restrict__ xi,
    const float* __restrict__ Bm, const float* __restrict__ Cm,
    const float* __restrict__ zs, const float* __restrict__ Dp,
    const float* __restrict__ H0, const float* __restrict__ A_log,
    float* __restrict__ y_out)
{
    const int tid = threadIdx.x;
    const int d   = tid >> 4;
    const int n   = tid & 15;
    const int b   = blockIdx.x >> 5;
    const int c   = blockIdx.x & 31;
    const int t0  = b * L_ + c * CHUNK;

    const float An  = -__expf(A_log[tid]);
    const float Dpd = Dp[d];

    const int u = ((b * DI + d) * NCHUNK + c) * DS + n;
    float h = H0[u];

    const float* pD = delta + (size_t)t0 * DI + d;
    const float* pX = xi    + (size_t)t0 * DI + d;
    const float* pZ = zs    + (size_t)t0 * DI + d;
    const float* pB = Bm    + (size_t)t0 * DS + n;
    const float* pC = Cm    + (size_t)t0 * DS + n;
    float*       pY = y_out + (size_t)t0 * DI + d;

#pragma unroll 4
    for (int i = 0; i < CHUNK; ++i) {
        const float del = pD[i * DI];
        const float xiv = pX[i * DI];
        const float Bv  = pB[i * DS];
        const float Cv  = pC[i * DS];
        const float a   = __expf(del * An);
        h = a * h + del * xiv * Bv;
        float p = h * Cv;
        DPP_ADD(p, 0xB1);    // + lane^1
        DPP_ADD(p, 0x4E);    // + lane^2   (quads uniform)
        DPP_ADD(p, 0x124);   // row_ror:4  (adds adjacent quad)
        DPP_ADD(p, 0x128);   // row_ror:8  (adds other 8-group -> full 16 sum)
        if (n == 0) pY[i * DI] = (p + xiv * Dpd) * pZ[i * DI];
    }
}

// ============ K5: two real FFTs per complex 2048-pt FFT, xfT (dm-major) out ============
__global__ __launch_bounds__(256) void k_fft(
    const float* __restrict__ x, float* __restrict__ xfT)
{
    __shared__ float re[2048], im[2048], twr[1024], twi[1024];
    const int tid = threadIdx.x;
    const int b   = blockIdx.x / (DM / 2);
    const int p   = blockIdx.x % (DM / 2);   // channel pair (2p, 2p+1)
    for (int j = tid; j < 1024; j += 256) {
        const float ang = -6.283185307179586f * (float)j * (1.0f / 2048.0f);
        float s, c;
        sincosf(ang, &s, &c);
        twr[j] = c; twi[j] = s;
    }
    for (int i = tid; i < 2048; i += 256) {
        const int r = (int)(__brev((unsigned)i) >> 21);
        const float2 v = *(const float2*)&x[(size_t)(b * L_ + i) * DM + 2 * p];
        re[r] = v.x;
        im[r] = v.y;
    }
    __syncthreads();
    for (int s = 1; s <= 11; ++s) {
        const int half  = 1 << (s - 1);
        const int tstep = 2048 >> s;
        for (int i = tid; i < 1024; i += 256) {
            const int j   = i & (half - 1);
            const int grp = i >> (s - 1);
            const int pos = (grp << s) + j;
            const float wr = twr[j * tstep], wi = twi[j * tstep];
            const float ar = re[pos + half], ai = im[pos + half];
            const float vr = wr * ar - wi * ai;
            const float vi = wr * ai + wi * ar;
            const float ur = re[pos], ui = im[pos];
            re[pos] = ur + vr;          im[pos] = ui + vi;
            re[pos + half] = ur - vr;   im[pos + half] = ui - vi;
        }
        __syncthreads();
    }
    // X1 = (Z[k]+conj(Z[N-k]))/2, X2 = (Z[k]-conj(Z[N-k]))/(2i)
    float* row1 = xfT + (size_t)(b * DM + 2 * p) * L_;
    float* row2 = row1 + L_;
    for (int k = tid; k < 2048; k += 256) {
        const int nk = (2048 - k) & 2047;
        const float zr = re[k],  zi = im[k];
        const float qr = re[nk], qi = im[nk];
        const float e1r = zr + qr, e1i = zi - qi;
        const float e2r = zr - qr, e2i = zi + qi;
        row1[k] = 0.5f * sqrtf(e1r * e1r + e1i * e1i);
        row2[k] = 0.5f * sqrtf(e2r * e2r + e2i * e2i);
    }
}

// ============ K6: tail, 2 threads per token (lo: proj/LN/FFN-half/head; hi: CNN/FFN-half) ====
// block = 256 threads = 128 tokens; grid = B * 16 = 1024 blocks
__global__ __launch_bounds__(256) void k_tail(
    const float* __restrict__ yg, const float* __restrict__ xfT,
    const float* __restrict__ out_w,
    const float* __restrict__ ln1_g, const float* __restrict__ ln1_b,
    const float* __restrict__ w1, const float* __restrict__ b1,
    const float* __restrict__ w2, const float* __restrict__ b2,
    const float* __restrict__ lng, const float* __restrict__ lnb,
    const float* __restrict__ cnn_w, const float* __restrict__ cnn_b,
    const float* __restrict__ l1w, const float* __restrict__ l1b,
    const float* __restrict__ l2w, const float* __restrict__ l2b,
    const float* __restrict__ l3w, const float* __restrict__ l3b,
    float* __restrict__ part)
{
    __shared__ float s_y[128][DI + 1];    // stride 25: conflict-free strided reads
    __shared__ float s_h[128][DM + 1];    // stride 13
    __shared__ float s_f2[128][DM + 1];
    __shared__ float s_o1[128][DM + 1];
    __shared__ float sred[256];

    const int tid = threadIdx.x;
    const int b   = blockIdx.x >> 4;
    const int l0  = (blockIdx.x & 15) << 7;
    const int tok = tid & 127;
    const int hi  = tid >> 7;             // wave-uniform role
    const int l   = l0 + tok;

    // stage y coalesced
    {
        const float* gy = yg + ((size_t)b * L_ + l0) * DI;
        for (int j = tid; j < 128 * DI; j += 256) s_y[j / DI][j % DI] = gy[j];
    }
    __syncthreads();

    float h[DM];
    float f2h[DM];
    if (!hi) {
        // out_proj + LN1
        float m[DM];
#pragma unroll
        for (int j = 0; j < DM; ++j) {
            float acc = 0.0f;
#pragma unroll
            for (int e = 0; e < DI; ++e) acc += s_y[tok][e] * out_w[j * DI + e];
            m[j] = acc;
        }
        float mean = 0.0f;
#pragma unroll
        for (int j = 0; j < DM; ++j) mean += m[j];
        mean *= (1.0f / DM);
        float var = 0.0f;
#pragma unroll
        for (int j = 0; j < DM; ++j) { const float dv = m[j] - mean; var += dv * dv; }
        var *= (1.0f / DM);
        const float inv1 = rsqrtf(var + 1e-12f);
#pragma unroll
        for (int j = 0; j < DM; ++j) {
            h[j] = (m[j] - mean) * inv1 * ln1_g[j] + ln1_b[j];
            s_h[tok][j] = h[j];
        }
    } else {
        // CNN on xf + xc-half of head l1
        float xfm[DM], xf0[DM], xfp[DM];
#pragma unroll
        for (int i = 0; i < DM; ++i) {
            const float* row = xfT + (size_t)(b * DM + i) * L_;
            xfm[i] = (l == 0)      ? 0.0f : row[l - 1];
            xf0[i] = row[l];
            xfp[i] = (l == L_ - 1) ? 0.0f : row[l + 1];
        }
#pragma unroll
        for (int o = 0; o < DM; ++o) {
            float acc = cnn_b[o];
#pragma unroll
            for (int i = 0; i < DM; ++i) {
                const int wb = (o * DM + i) * 3;
                acc += xfm[i] * cnn_w[wb] + xf0[i] * cnn_w[wb + 1] + xfp[i] * cnn_w[wb + 2];
            }
            f2h[o] = acc;   // reuse f2h as xc temporarily
        }
        // o1 partial from xc
#pragma unroll
        for (int dd = 0; dd < DM; ++dd) {
            float acc = 0.0f;
#pragma unroll
            for (int e = 0; e < DM; ++e) acc += f2h[e] * l1w[dd * (2 * DM) + DM + e];
            s_o1[tok][dd] = acc;
        }
    }
    __syncthreads();

    // FFN half (both roles): e in [hi*24, hi*24+24)
    if (hi) {
#pragma unroll
        for (int j = 0; j < DM; ++j) h[j] = s_h[tok][j];
    }
#pragma unroll
    for (int j = 0; j < DM; ++j) f2h[j] = 0.0f;
    const int e0 = hi * 24;
#pragma unroll
    for (int e = 0; e < 24; ++e) {
        float acc = b1[e0 + e];
#pragma unroll
        for (int j = 0; j < DM; ++j) acc += h[j] * w1[(e0 + e) * DM + j];
        const float ffe = geluf(acc);
#pragma unroll
        for (int j = 0; j < DM; ++j) f2h[j] += ffe * w2[j * (4 * DM) + e0 + e];
    }
    if (hi) {
#pragma unroll
        for (int j = 0; j < DM; ++j) s_f2[tok][j] = f2h[j];
    }
    __syncthreads();

    float o3 = 0.0f;
    if (!hi) {
        float f2[DM];
#pragma unroll
        for (int j = 0; j < DM; ++j) f2[j] = f2h[j] + s_f2[tok][j] + b2[j] + h[j];
        float mean = 0.0f;
#pragma unroll
        for (int j = 0; j < DM; ++j) mean += f2[j];
        mean *= (1.0f / DM);
        float var = 0.0f;
#pragma unroll
        for (int j = 0; j < DM; ++j) { const float dv = f2[j] - mean; var += dv * dv; }
        var *= (1.0f / DM);
        const float inv2 = rsqrtf(var + 1e-12f);
        float xm[DM];
#pragma unroll
        for (int j = 0; j < DM; ++j) xm[j] = (f2[j] - mean) * inv2 * lng[j] + lnb[j];

        float o1[DM];
#pragma unroll
        for (int dd = 0; dd < DM; ++dd) {
            float acc = l1b[dd] + s_o1[tok][dd];
#pragma unroll
            for (int e = 0; e < DM; ++e) acc += xm[e] * l1w[dd * (2 * DM) + e];
            o1[dd] = eluf(acc);
        }
        float o2[20];
#pragma unroll
        for (int e = 0; e < 20; ++e) {
            float acc = l2b[e];
#pragma unroll
            for (int dd = 0; dd < DM; ++dd) acc += o1[dd] * l2w[e * DM + dd];
            o2[e] = acc;
        }
        o3 = l3b[0];
#pragma unroll
        for (int e = 0; e < 20; ++e) o3 += o2[e] * l3w[e];
    }

    sred[tid] = o3;
    __syncthreads();
    for (int s = 128; s > 0; s >>= 1) {
        if (tid < s) sred[tid] += sred[tid + s];
        __syncthreads();
    }
    if (tid == 0) part[blockIdx.x] = sred[0];
}

// ============ K7: final per-batch mean + sigmoid ============
__global__ void k_final(const float* __restrict__ part, float* __restrict__ out)
{
    const int b = threadIdx.x;
    if (b < B_) {
        float s = 0.0f;
        for (int i = 0; i < 16; ++i) s += part[b * 16 + i];
        s *= (1.0f / (float)L_);
        out[b] = 1.0f / (1.0f + __expf(-s));
    }
}

extern "C" void kernel_launch(void* const* d_in, const int* in_sizes, int n_in,
                              void* d_out, int out_size, void* d_ws, size_t ws_size,
                              hipStream_t stream)
{
    const float* x        = (const float*)d_in[0];
    const float* in_w     = (const float*)d_in[1];
    const float* conv_w   = (const float*)d_in[2];
    const float* conv_b   = (const float*)d_in[3];
    const float* xproj_w  = (const float*)d_in[4];
    const float* dt_w     = (const float*)d_in[5];
    const float* dt_b     = (const float*)d_in[6];
    const float* A_log    = (const float*)d_in[7];
    const float* Dp       = (const float*)d_in[8];
    const float* out_w    = (const float*)d_in[9];
    const float* ln1_g    = (const float*)d_in[10];
    const float* ln1_b    = (const float*)d_in[11];
    const float* ffn_w1   = (const float*)d_in[12];
    const float* ffn_b1   = (const float*)d_in[13];
    const float* ffn_w2   = (const float*)d_in[14];
    const float* ffn_b2   = (const float*)d_in[15];
    const float* ffn_ln_g = (const float*)d_in[16];
    const float* ffn_ln_b = (const float*)d_in[17];
    const float* cnn_w    = (const float*)d_in[18];
    const float* cnn_b    = (const float*)d_in[19];
    const float* l1w      = (const float*)d_in[20];
    const float* l1b      = (const float*)d_in[21];
    const float* l2w      = (const float*)d_in[22];
    const float* l2b      = (const float*)d_in[23];
    const float* l3w      = (const float*)d_in[24];
    const float* l3b      = (const float*)d_in[25];
    float* out = (float*)d_out;

    float* ws = (float*)d_ws;
    const size_t nTDI = (size_t)T_ * DI;
    const size_t nTDS = (size_t)T_ * DS;
    const size_t nU   = (size_t)B_ * DI * NCHUNK * DS;   // 786,432
    float* w_delta = ws;
    float* w_xi    = w_delta + nTDI;
    float* w_zs    = w_xi + nTDI;
    float* w_y     = w_zs + nTDI;
    float* w_Bm    = w_y + nTDI;
    float* w_Cm    = w_Bm + nTDS;
    float* w_P     = w_Cm + nTDS;
    float* w_H     = w_P + nU;
    float* w_H0    = w_H + nU;
    float* w_part  = w_H0 + nU;
    float* w_xfT   = w_P;          // alias: P+H (1,572,864 floats) dead after scan2

    k_proj<<<512, 256, 0, stream>>>(x, in_w, conv_w, conv_b, xproj_w, dt_w, dt_b,
                                    w_xi, w_zs, w_delta, w_Bm, w_Cm);
    k_scan1<<<B_ * NCHUNK, 384, 0, stream>>>(w_delta, w_xi, w_Bm, A_log, w_P, w_H);
    k_scan2<<<96, 256, 0, stream>>>(w_P, w_H, w_H0);
    k_fft<<<B_ * (DM / 2), 256, 0, stream>>>(x, w_xfT);   // overwrites P,H (now dead)
    k_scan3<<<B_ * NCHUNK, 384, 0, stream>>>(w_delta, w_xi, w_Bm, w_Cm, w_zs, Dp,
                                             w_H0, A_log, w_y);
    k_tail<<<B_ * 16, 256, 0, stream>>>(w_y, w_xfT, out_w,
                                    ln1_g, ln1_b, ffn_w1, ffn_b1, ffn_w2, ffn_b2,
                                    ffn_ln_g, ffn_ln_b, cnn_w, cnn_b,
                                    l1w, l1b, l2w, l2b, l3w, l3b, w_part);
    k_final<<<1, 64, 0, stream>>>(w_part, out);
}

// Round 8
// 210.186 us; speedup vs baseline: 1.1910x; 1.1910x over previous
//
#include <hip/hip_runtime.h>
#include <math.h>

#define B_  64
#define L_  2048
#define DM  12
#define DI  24
#define DS  16
#define DC  4
#define DTR 1
#define T_  (B_ * L_)        // 131072 tokens
#define NCHUNK 64
#define CHUNK  32            // L_ / NCHUNK

// ---------------- ws layout (floats) — total 16,912,640 (~68 MB < proven 78 MB) ----
// xi  : T*DI   3,145,728
// zs  : T*DI   3,145,728
// y   : T*DI   3,145,728   (gated scan output, t-major)
// dt  : T_       131,072   (raw dt scalar per token; delta recomputed on the fly)
// Bm  : T*DS   2,097,152
// Cm  : T*DS   2,097,152
// Sd  : B*DI*NCHUNK          98,304   (per-chunk sum of delta)
// H   : B*DI*NCHUNK*DS    1,572,864   \ aliased as xf (B*DM*L = 1,572,864) after scan2
// H0  : B*DI*NCHUNK*DS    1,572,864
// part: 1024

__device__ __forceinline__ float siluf(float v)  { return v / (1.0f + __expf(-v)); }
__device__ __forceinline__ float geluf(float v) {
    return 0.5f * v * (1.0f + erff(v * 0.70710678118654752440f));
}
__device__ __forceinline__ float eluf(float v) { return v > 0.0f ? v : __expf(v) - 1.0f; }

// ============ K1: in_proj + depthwise causal conv + silu + x_proj; stores raw dt ============
__global__ __launch_bounds__(256) void k_proj(
    const float* __restrict__ x, const float* __restrict__ w_in,
    const float* __restrict__ conv_w, const float* __restrict__ conv_b,
    const float* __restrict__ xproj_w,
    float* __restrict__ xi_out, float* __restrict__ zs_out,
    float* __restrict__ dt_out, float* __restrict__ Bm_out,
    float* __restrict__ Cm_out)
{
    __shared__ float s_xi[256 + 3][DI + 1];
    const int tid = threadIdx.x;
    const int b   = blockIdx.x >> 3;
    const int l0  = (blockIdx.x & 7) << 8;
    const int l   = l0 + tid;
    const int t   = b * L_ + l;

    float xv[DM];
    *(float4*)&xv[0] = *(const float4*)&x[t * DM + 0];
    *(float4*)&xv[4] = *(const float4*)&x[t * DM + 4];
    *(float4*)&xv[8] = *(const float4*)&x[t * DM + 8];

#pragma unroll
    for (int e = 0; e < DI; ++e) {
        float acc = 0.0f;
#pragma unroll
        for (int d = 0; d < DM; ++d) acc += xv[d] * w_in[(DI + e) * DM + d];
        zs_out[t * DI + e] = siluf(acc);
    }
#pragma unroll
    for (int e = 0; e < DI; ++e) {
        float acc = 0.0f;
#pragma unroll
        for (int d = 0; d < DM; ++d) acc += xv[d] * w_in[e * DM + d];
        s_xi[tid + 3][e] = acc;
    }
    if (tid < 3) {
        const int lh = l0 - 3 + tid;
        if (lh < 0) {
            for (int e = 0; e < DI; ++e) s_xi[tid][e] = 0.0f;
        } else {
            const int th = b * L_ + lh;
            float xh[DM];
            for (int d = 0; d < DM; ++d) xh[d] = x[th * DM + d];
            for (int e = 0; e < DI; ++e) {
                float acc = 0.0f;
                for (int d = 0; d < DM; ++d) acc += xh[d] * w_in[e * DM + d];
                s_xi[tid][e] = acc;
            }
        }
    }
    __syncthreads();

    float xi[DI];
#pragma unroll
    for (int dch = 0; dch < DI; ++dch) {
        float acc = conv_b[dch];
#pragma unroll
        for (int k = 0; k < DC; ++k) acc += s_xi[tid + k][dch] * conv_w[dch * DC + k];
        xi[dch] = siluf(acc);
        xi_out[t * DI + dch] = xi[dch];
    }

    float dt = 0.0f;
#pragma unroll
    for (int d = 0; d < DI; ++d) dt += xi[d] * xproj_w[d];
    dt_out[t] = dt;
#pragma unroll
    for (int e = 0; e < DS; ++e) {
        float accB = 0.0f, accC = 0.0f;
#pragma unroll
        for (int d = 0; d < DI; ++d) {
            accB += xi[d] * xproj_w[(1 + e) * DI + d];
            accC += xi[d] * xproj_w[(1 + DS + e) * DI + d];
        }
        Bm_out[t * DS + e] = accB;
        Cm_out[t * DS + e] = accC;
    }
}

// ============ S1: local chunk scan — lane owns (b,c,d) with ALL 16 n-states ============
// block = 384 threads = 16 chunks x 24 d; grid = B * (NCHUNK/16) = 256 blocks
__global__ __launch_bounds__(384) void k_scan1(
    const float* __restrict__ dt_in, const float* __restrict__ xi,
    const float* __restrict__ Bm, const float* __restrict__ A_log,
    const float* __restrict__ dt_w, const float* __restrict__ dt_b,
    float* __restrict__ Sd, float* __restrict__ H)
{
    const int tid = threadIdx.x;
    const int d   = tid % DI;
    const int cl  = tid / DI;             // 0..15
    const int b   = blockIdx.x >> 2;
    const int c   = ((blockIdx.x & 3) << 4) + cl;
    const int t0  = b * L_ + c * CHUNK;

    float An[DS];
#pragma unroll
    for (int j = 0; j < DS; ++j) An[j] = -__expf(A_log[d * DS + j]);
    const float dtw = dt_w[d], dtb = dt_b[d];

    float h[DS];
#pragma unroll
    for (int j = 0; j < DS; ++j) h[j] = 0.0f;
    float sumdel = 0.0f;

    const float*  pDt = dt_in + t0;
    const float*  pX  = xi + (size_t)t0 * DI + d;
    const float4* pB  = (const float4*)(Bm + (size_t)t0 * DS);

#pragma unroll 4
    for (int i = 0; i < CHUNK; ++i) {
        const float v = fmaf(pDt[i], dtw, dtb);
        const float e = __expf(v);
        const float delta = (v > 20.0f) ? v : __logf(1.0f + e);
        const float u = delta * pX[i * DI];
        sumdel += delta;
        const float4 B0 = pB[i * 4 + 0];
        const float4 B1 = pB[i * 4 + 1];
        const float4 B2 = pB[i * 4 + 2];
        const float4 B3 = pB[i * 4 + 3];
        const float* Bp = &B0.x;
#pragma unroll
        for (int j = 0; j < DS; ++j) {
            const float a = __expf(delta * An[j]);
            h[j] = a * h[j] + u * ((j < 4) ? (&B0.x)[j] : (j < 8) ? (&B1.x)[j - 4]
                                   : (j < 12) ? (&B2.x)[j - 8] : (&B3.x)[j - 12]);
        }
        (void)Bp;
    }
    const int cu = (b * DI + d) * NCHUNK + c;
    Sd[cu] = sumdel;
    float4* pH = (float4*)(H + (size_t)cu * DS);
    pH[0] = make_float4(h[0], h[1], h[2], h[3]);
    pH[1] = make_float4(h[4], h[5], h[6], h[7]);
    pH[2] = make_float4(h[8], h[9], h[10], h[11]);
    pH[3] = make_float4(h[12], h[13], h[14], h[15]);
}

// ============ S2: combine chunk summaries; P_n rebuilt as exp(An * Sd) ============
__global__ __launch_bounds__(256) void k_scan2(
    const float* __restrict__ Sd, const float* __restrict__ H,
    const float* __restrict__ A_log, float* __restrict__ H0)
{
    const int idx  = blockIdx.x * 256 + threadIdx.x;  // 24576 = (b*DI+d)*16 + n
    const int n    = idx & 15;
    const int rest = idx >> 4;                        // b*DI + d
    const int d    = rest % DI;
    const float An = -__expf(A_log[d * DS + n]);
    float Hc = 0.0f;
    for (int c = 0; c < NCHUNK; ++c) {
        const float a = __expf(An * Sd[rest * NCHUNK + c]);
        const int u = (rest * NCHUNK + c) * DS + n;
        H0[u] = Hc;
        Hc = a * Hc + H[u];
    }
}

// ============ S3: replay with h0 + fused gate; all-n in-lane, y in-register dot ============
__global__ __launch_bounds__(384) void k_scan3(
    const float* __restrict__ dt_in, const float* __restrict__ xi,
    const float* __restrict__ Bm, const float* __restrict__ Cm,
    const float* __restrict__ zs, const float* __restrict__ Dp,
    const float* __restrict__ H0, const float* __restrict__ A_log,
    const float* __restrict__ dt_w, const float* __restrict__ dt_b,
    float* __restrict__ y_out)
{
    const int tid = threadIdx.x;
    const int d   = tid % DI;
    const int cl  = tid / DI;
    const int b   = blockIdx.x >> 2;
    const int c   = ((blockIdx.x & 3) << 4) + cl;
    const int t0  = b * L_ + c * CHUNK;

    float An[DS];
#pragma unroll
    for (int j = 0; j < DS; ++j) An[j] = -__expf(A_log[d * DS + j]);
    const float dtw = dt_w[d], dtb = dt_b[d];
    const float Dpd = Dp[d];

    const int cu = (b * DI + d) * NCHUNK + c;
    float h[DS];
    {
        const float4* pH0 = (const float4*)(H0 + (size_t)cu * DS);
        const float4 a0 = pH0[0], a1 = pH0[1], a2 = pH0[2], a3 = pH0[3];
        h[0]=a0.x; h[1]=a0.y; h[2]=a0.z; h[3]=a0.w;
        h[4]=a1.x; h[5]=a1.y; h[6]=a1.z; h[7]=a1.w;
        h[8]=a2.x; h[9]=a2.y; h[10]=a2.z; h[11]=a2.w;
        h[12]=a3.x; h[13]=a3.y; h[14]=a3.z; h[15]=a3.w;
    }

    const float*  pDt = dt_in + t0;
    const float*  pX  = xi + (size_t)t0 * DI + d;
    const float*  pZ  = zs + (size_t)t0 * DI + d;
    const float4* pB  = (const float4*)(Bm + (size_t)t0 * DS);
    const float4* pC  = (const float4*)(Cm + (size_t)t0 * DS);
    float*        pY  = y_out + (size_t)t0 * DI + d;

#pragma unroll 4
    for (int i = 0; i < CHUNK; ++i) {
        const float v = fmaf(pDt[i], dtw, dtb);
        const float e = __expf(v);
        const float delta = (v > 20.0f) ? v : __logf(1.0f + e);
        const float xiv = pX[i * DI];
        const float u = delta * xiv;
        const float4 B0 = pB[i * 4 + 0];
        const float4 B1 = pB[i * 4 + 1];
        const float4 B2 = pB[i * 4 + 2];
        const float4 B3 = pB[i * 4 + 3];
        const float4 C0 = pC[i * 4 + 0];
        const float4 C1 = pC[i * 4 + 1];
        const float4 C2 = pC[i * 4 + 2];
        const float4 C3 = pC[i * 4 + 3];
        float p = 0.0f;
#pragma unroll
        for (int j = 0; j < DS; ++j) {
            const float a = __expf(delta * An[j]);
            const float Bj = (j < 4) ? (&B0.x)[j] : (j < 8) ? (&B1.x)[j - 4]
                             : (j < 12) ? (&B2.x)[j - 8] : (&B3.x)[j - 12];
            const float Cj = (j < 4) ? (&C0.x)[j] : (j < 8) ? (&C1.x)[j - 4]
                             : (j < 12) ? (&C2.x)[j - 8] : (&C3.x)[j - 12];
            h[j] = a * h[j] + u * Bj;
            p += h[j] * Cj;
        }
        pY[i * DI] = (p + xiv * Dpd) * pZ[i * DI];
    }
}

// ============ K5: two real FFTs per complex 2048-pt FFT, xfT (dm-major) out ============
__global__ __launch_bounds__(256) void k_fft(
    const float* __restrict__ x, float* __restrict__ xfT)
{
    __shared__ float re[2048], im[2048], twr[1024], twi[1024];
    const int tid = threadIdx.x;
    const int b   = blockIdx.x / (DM / 2);
    const int p   = blockIdx.x % (DM / 2);   // channel pair (2p, 2p+1)
    for (int j = tid; j < 1024; j += 256) {
        const float ang = -6.283185307179586f * (float)j * (1.0f / 2048.0f);
        float s, c;
        sincosf(ang, &s, &c);
        twr[j] = c; twi[j] = s;
    }
    for (int i = tid; i < 2048; i += 256) {
        const int r = (int)(__brev((unsigned)i) >> 21);
        const float2 v = *(const float2*)&x[(size_t)(b * L_ + i) * DM + 2 * p];
        re[r] = v.x;
        im[r] = v.y;
    }
    __syncthreads();
    for (int s = 1; s <= 11; ++s) {
        const int half  = 1 << (s - 1);
        const int tstep = 2048 >> s;
        for (int i = tid; i < 1024; i += 256) {
            const int j   = i & (half - 1);
            const int grp = i >> (s - 1);
            const int pos = (grp << s) + j;
            const float wr = twr[j * tstep], wi = twi[j * tstep];
            const float ar = re[pos + half], ai = im[pos + half];
            const float vr = wr * ar - wi * ai;
            const float vi = wr * ai + wi * ar;
            const float ur = re[pos], ui = im[pos];
            re[pos] = ur + vr;          im[pos] = ui + vi;
            re[pos + half] = ur - vr;   im[pos + half] = ui - vi;
        }
        __syncthreads();
    }
    float* row1 = xfT + (size_t)(b * DM + 2 * p) * L_;
    float* row2 = row1 + L_;
    for (int k = tid; k < 2048; k += 256) {
        const int nk = (2048 - k) & 2047;
        const float zr = re[k],  zi = im[k];
        const float qr = re[nk], qi = im[nk];
        const float e1r = zr + qr, e1i = zi - qi;
        const float e2r = zr - qr, e2i = zi + qi;
        row1[k] = 0.5f * sqrtf(e1r * e1r + e1i * e1i);
        row2[k] = 0.5f * sqrtf(e2r * e2r + e2i * e2i);
    }
}

// ============ K6: tail, 2 threads per token ============
__global__ __launch_bounds__(256) void k_tail(
    const float* __restrict__ yg, const float* __restrict__ xfT,
    const float* __restrict__ out_w,
    const float* __restrict__ ln1_g, const float* __restrict__ ln1_b,
    const float* __restrict__ w1, const float* __restrict__ b1,
    const float* __restrict__ w2, const float* __restrict__ b2,
    const float* __restrict__ lng, const float* __restrict__ lnb,
    const float* __restrict__ cnn_w, const float* __restrict__ cnn_b,
    const float* __restrict__ l1w, const float* __restrict__ l1b,
    const float* __restrict__ l2w, const float* __restrict__ l2b,
    const float* __restrict__ l3w, const float* __restrict__ l3b,
    float* __restrict__ part)
{
    __shared__ float s_y[128][DI + 1];
    __shared__ float s_h[128][DM + 1];
    __shared__ float s_f2[128][DM + 1];
    __shared__ float s_o1[128][DM + 1];
    __shared__ float sred[256];

    const int tid = threadIdx.x;
    const int b   = blockIdx.x >> 4;
    const int l0  = (blockIdx.x & 15) << 7;
    const int tok = tid & 127;
    const int hi  = tid >> 7;
    const int l   = l0 + tok;

    {
        const float* gy = yg + ((size_t)b * L_ + l0) * DI;
        for (int j = tid; j < 128 * DI; j += 256) s_y[j / DI][j % DI] = gy[j];
    }
    __syncthreads();

    float h[DM];
    float f2h[DM];
    if (!hi) {
        float m[DM];
#pragma unroll
        for (int j = 0; j < DM; ++j) {
            float acc = 0.0f;
#pragma unroll
            for (int e = 0; e < DI; ++e) acc += s_y[tok][e] * out_w[j * DI + e];
            m[j] = acc;
        }
        float mean = 0.0f;
#pragma unroll
        for (int j = 0; j < DM; ++j) mean += m[j];
        mean *= (1.0f / DM);
        float var = 0.0f;
#pragma unroll
        for (int j = 0; j < DM; ++j) { const float dv = m[j] - mean; var += dv * dv; }
        var *= (1.0f / DM);
        const float inv1 = rsqrtf(var + 1e-12f);
#pragma unroll
        for (int j = 0; j < DM; ++j) {
            h[j] = (m[j] - mean) * inv1 * ln1_g[j] + ln1_b[j];
            s_h[tok][j] = h[j];
        }
    } else {
        float xfm[DM], xf0[DM], xfp[DM];
#pragma unroll
        for (int i = 0; i < DM; ++i) {
            const float* row = xfT + (size_t)(b * DM + i) * L_;
            xfm[i] = (l == 0)      ? 0.0f : row[l - 1];
            xf0[i] = row[l];
            xfp[i] = (l == L_ - 1) ? 0.0f : row[l + 1];
        }
#pragma unroll
        for (int o = 0; o < DM; ++o) {
            float acc = cnn_b[o];
#pragma unroll
            for (int i = 0; i < DM; ++i) {
                const int wb = (o * DM + i) * 3;
                acc += xfm[i] * cnn_w[wb] + xf0[i] * cnn_w[wb + 1] + xfp[i] * cnn_w[wb + 2];
            }
            f2h[o] = acc;
        }
#pragma unroll
        for (int dd = 0; dd < DM; ++dd) {
            float acc = 0.0f;
#pragma unroll
            for (int e = 0; e < DM; ++e) acc += f2h[e] * l1w[dd * (2 * DM) + DM + e];
            s_o1[tok][dd] = acc;
        }
    }
    __syncthreads();

    if (hi) {
#pragma unroll
        for (int j = 0; j < DM; ++j) h[j] = s_h[tok][j];
    }
#pragma unroll
    for (int j = 0; j < DM; ++j) f2h[j] = 0.0f;
    const int e0 = hi * 24;
#pragma unroll
    for (int e = 0; e < 24; ++e) {
        float acc = b1[e0 + e];
#pragma unroll
        for (int j = 0; j < DM; ++j) acc += h[j] * w1[(e0 + e) * DM + j];
        const float ffe = geluf(acc);
#pragma unroll
        for (int j = 0; j < DM; ++j) f2h[j] += ffe * w2[j * (4 * DM) + e0 + e];
    }
    if (hi) {
#pragma unroll
        for (int j = 0; j < DM; ++j) s_f2[tok][j] = f2h[j];
    }
    __syncthreads();

    float o3 = 0.0f;
    if (!hi) {
        float f2[DM];
#pragma unroll
        for (int j = 0; j < DM; ++j) f2[j] = f2h[j] + s_f2[tok][j] + b2[j] + h[j];
        float mean = 0.0f;
#pragma unroll
        for (int j = 0; j < DM; ++j) mean += f2[j];
        mean *= (1.0f / DM);
        float var = 0.0f;
#pragma unroll
        for (int j = 0; j < DM; ++j) { const float dv = f2[j] - mean; var += dv * dv; }
        var *= (1.0f / DM);
        const float inv2 = rsqrtf(var + 1e-12f);
        float xm[DM];
#pragma unroll
        for (int j = 0; j < DM; ++j) xm[j] = (f2[j] - mean) * inv2 * lng[j] + lnb[j];

        float o1[DM];
#pragma unroll
        for (int dd = 0; dd < DM; ++dd) {
            float acc = l1b[dd] + s_o1[tok][dd];
#pragma unroll
            for (int e = 0; e < DM; ++e) acc += xm[e] * l1w[dd * (2 * DM) + e];
            o1[dd] = eluf(acc);
        }
        float o2[20];
#pragma unroll
        for (int e = 0; e < 20; ++e) {
            float acc = l2b[e];
#pragma unroll
            for (int dd = 0; dd < DM; ++dd) acc += o1[dd] * l2w[e * DM + dd];
            o2[e] = acc;
        }
        o3 = l3b[0];
#pragma unroll
        for (int e = 0; e < 20; ++e) o3 += o2[e] * l3w[e];
    }

    sred[tid] = o3;
    __syncthreads();
    for (int s = 128; s > 0; s >>= 1) {
        if (tid < s) sred[tid] += sred[tid + s];
        __syncthreads();
    }
    if (tid == 0) part[blockIdx.x] = sred[0];
}

// ============ K7: final per-batch mean + sigmoid ============
__global__ void k_final(const float* __restrict__ part, float* __restrict__ out)
{
    const int b = threadIdx.x;
    if (b < B_) {
        float s = 0.0f;
        for (int i = 0; i < 16; ++i) s += part[b * 16 + i];
        s *= (1.0f / (float)L_);
        out[b] = 1.0f / (1.0f + __expf(-s));
    }
}

extern "C" void kernel_launch(void* const* d_in, const int* in_sizes, int n_in,
                              void* d_out, int out_size, void* d_ws, size_t ws_size,
                              hipStream_t stream)
{
    const float* x        = (const float*)d_in[0];
    const float* in_w     = (const float*)d_in[1];
    const float* conv_w   = (const float*)d_in[2];
    const float* conv_b   = (const float*)d_in[3];
    const float* xproj_w  = (const float*)d_in[4];
    const float* dt_w     = (const float*)d_in[5];
    const float* dt_b     = (const float*)d_in[6];
    const float* A_log    = (const float*)d_in[7];
    const float* Dp       = (const float*)d_in[8];
    const float* out_w    = (const float*)d_in[9];
    const float* ln1_g    = (const float*)d_in[10];
    const float* ln1_b    = (const float*)d_in[11];
    const float* ffn_w1   = (const float*)d_in[12];
    const float* ffn_b1   = (const float*)d_in[13];
    const float* ffn_w2   = (const float*)d_in[14];
    const float* ffn_b2   = (const float*)d_in[15];
    const float* ffn_ln_g = (const float*)d_in[16];
    const float* ffn_ln_b = (const float*)d_in[17];
    const float* cnn_w    = (const float*)d_in[18];
    const float* cnn_b    = (const float*)d_in[19];
    const float* l1w      = (const float*)d_in[20];
    const float* l1b      = (const float*)d_in[21];
    const float* l2w      = (const float*)d_in[22];
    const float* l2b      = (const float*)d_in[23];
    const float* l3w      = (const float*)d_in[24];
    const float* l3b      = (const float*)d_in[25];
    float* out = (float*)d_out;

    float* ws = (float*)d_ws;
    const size_t nTDI = (size_t)T_ * DI;
    const size_t nTDS = (size_t)T_ * DS;
    const size_t nCH  = (size_t)B_ * DI * NCHUNK;        // 98,304
    float* w_xi   = ws;
    float* w_zs   = w_xi + nTDI;
    float* w_y    = w_zs + nTDI;
    float* w_dt   = w_y + nTDI;
    float* w_Bm   = w_dt + T_;
    float* w_Cm   = w_Bm + nTDS;
    float* w_Sd   = w_Cm + nTDS;
    float* w_H    = w_Sd + nCH;
    float* w_H0   = w_H + nCH * DS;
    float* w_part = w_H0 + nCH * DS;
    float* w_xfT  = w_H;           // alias: H (1,572,864 floats) dead after scan2

    k_proj<<<512, 256, 0, stream>>>(x, in_w, conv_w, conv_b, xproj_w,
                                    w_xi, w_zs, w_dt, w_Bm, w_Cm);
    k_scan1<<<B_ * (NCHUNK / 16), 384, 0, stream>>>(w_dt, w_xi, w_Bm, A_log,
                                                    dt_w, dt_b, w_Sd, w_H);
    k_scan2<<<96, 256, 0, stream>>>(w_Sd, w_H, A_log, w_H0);
    k_fft<<<B_ * (DM / 2), 256, 0, stream>>>(x, w_xfT);   // overwrites H (now dead)
    k_scan3<<<B_ * (NCHUNK / 16), 384, 0, stream>>>(w_dt, w_xi, w_Bm, w_Cm, w_zs, Dp,
                                                    w_H0, A_log, dt_w, dt_b, w_y);
    k_tail<<<B_ * 16, 256, 0, stream>>>(w_y, w_xfT, out_w,
                                    ln1_g, ln1_b, ffn_w1, ffn_b1, ffn_w2, ffn_b2,
                                    ffn_ln_g, ffn_ln_b, cnn_w, cnn_b,
                                    l1w, l1b, l2w, l2b, l3w, l3b, w_part);
    k_final<<<1, 64, 0, stream>>>(w_part, out);
}

// Round 9
// 191.320 us; speedup vs baseline: 1.3085x; 1.0986x over previous
//
#include <hip/hip_runtime.h>
#include <math.h>

#define B_  64
#define L_  2048
#define DM  12
#define DI  24
#define DS  16
#define DC  4
#define DTR 1
#define T_  (B_ * L_)        // 131072 tokens
#define NCHUNK 64
#define CHUNK  32            // L_ / NCHUNK

// ---------------- ws layout (floats) — identical to round 8 (passed) ----
// xi  : T*DI   3,145,728
// zs  : T*DI   3,145,728
// y   : T*DI   3,145,728
// dt  : T_       131,072
// Bm  : T*DS   2,097,152
// Cm  : T*DS   2,097,152
// Sd  : B*DI*NCHUNK          98,304
// H   : B*DI*NCHUNK*DS    1,572,864   (aliased as xf after scan2)
// H0  : B*DI*NCHUNK*DS    1,572,864
// part: 1024

__device__ __forceinline__ float siluf(float v)  { return v / (1.0f + __expf(-v)); }
__device__ __forceinline__ float geluf(float v) {
    return 0.5f * v * (1.0f + erff(v * 0.70710678118654752440f));
}
__device__ __forceinline__ float eluf(float v) { return v > 0.0f ? v : __expf(v) - 1.0f; }

// ============ K1: in_proj + depthwise causal conv + silu + x_proj; stores raw dt ============
__global__ __launch_bounds__(256) void k_proj(
    const float* __restrict__ x, const float* __restrict__ w_in,
    const float* __restrict__ conv_w, const float* __restrict__ conv_b,
    const float* __restrict__ xproj_w,
    float* __restrict__ xi_out, float* __restrict__ zs_out,
    float* __restrict__ dt_out, float* __restrict__ Bm_out,
    float* __restrict__ Cm_out)
{
    __shared__ float s_xi[256 + 3][DI + 1];
    const int tid = threadIdx.x;
    const int b   = blockIdx.x >> 3;
    const int l0  = (blockIdx.x & 7) << 8;
    const int l   = l0 + tid;
    const int t   = b * L_ + l;

    float xv[DM];
    *(float4*)&xv[0] = *(const float4*)&x[t * DM + 0];
    *(float4*)&xv[4] = *(const float4*)&x[t * DM + 4];
    *(float4*)&xv[8] = *(const float4*)&x[t * DM + 8];

#pragma unroll
    for (int e = 0; e < DI; ++e) {
        float acc = 0.0f;
#pragma unroll
        for (int d = 0; d < DM; ++d) acc += xv[d] * w_in[(DI + e) * DM + d];
        zs_out[t * DI + e] = siluf(acc);
    }
#pragma unroll
    for (int e = 0; e < DI; ++e) {
        float acc = 0.0f;
#pragma unroll
        for (int d = 0; d < DM; ++d) acc += xv[d] * w_in[e * DM + d];
        s_xi[tid + 3][e] = acc;
    }
    if (tid < 3) {
        const int lh = l0 - 3 + tid;
        if (lh < 0) {
            for (int e = 0; e < DI; ++e) s_xi[tid][e] = 0.0f;
        } else {
            const int th = b * L_ + lh;
            float xh[DM];
            for (int d = 0; d < DM; ++d) xh[d] = x[th * DM + d];
            for (int e = 0; e < DI; ++e) {
                float acc = 0.0f;
                for (int d = 0; d < DM; ++d) acc += xh[d] * w_in[e * DM + d];
                s_xi[tid][e] = acc;
            }
        }
    }
    __syncthreads();

    float xi[DI];
#pragma unroll
    for (int dch = 0; dch < DI; ++dch) {
        float acc = conv_b[dch];
#pragma unroll
        for (int k = 0; k < DC; ++k) acc += s_xi[tid + k][dch] * conv_w[dch * DC + k];
        xi[dch] = siluf(acc);
        xi_out[t * DI + dch] = xi[dch];
    }

    float dt = 0.0f;
#pragma unroll
    for (int d = 0; d < DI; ++d) dt += xi[d] * xproj_w[d];
    dt_out[t] = dt;
#pragma unroll
    for (int e = 0; e < DS; ++e) {
        float accB = 0.0f, accC = 0.0f;
#pragma unroll
        for (int d = 0; d < DI; ++d) {
            accB += xi[d] * xproj_w[(1 + e) * DI + d];
            accC += xi[d] * xproj_w[(1 + DS + e) * DI + d];
        }
        Bm_out[t * DS + e] = accB;
        Cm_out[t * DS + e] = accC;
    }
}

// ============ S1: local chunk scan — lane owns (b,c,d) with ALL 16 n-states ============
__global__ __launch_bounds__(384) void k_scan1(
    const float* __restrict__ dt_in, const float* __restrict__ xi,
    const float* __restrict__ Bm, const float* __restrict__ A_log,
    const float* __restrict__ dt_w, const float* __restrict__ dt_b,
    float* __restrict__ Sd, float* __restrict__ H)
{
    const int tid = threadIdx.x;
    const int d   = tid % DI;
    const int cl  = tid / DI;             // 0..15
    const int b   = blockIdx.x >> 2;
    const int c   = ((blockIdx.x & 3) << 4) + cl;
    const int t0  = b * L_ + c * CHUNK;

    float An[DS];
#pragma unroll
    for (int j = 0; j < DS; ++j) An[j] = -__expf(A_log[d * DS + j]);
    const float dtw = dt_w[d], dtb = dt_b[d];

    float h[DS];
#pragma unroll
    for (int j = 0; j < DS; ++j) h[j] = 0.0f;
    float sumdel = 0.0f;

    const float*  pDt = dt_in + t0;
    const float*  pX  = xi + (size_t)t0 * DI + d;
    const float4* pB  = (const float4*)(Bm + (size_t)t0 * DS);

#pragma unroll 4
    for (int i = 0; i < CHUNK; ++i) {
        const float v = fmaf(pDt[i], dtw, dtb);
        const float e = __expf(v);
        const float delta = (v > 20.0f) ? v : __logf(1.0f + e);
        const float u = delta * pX[i * DI];
        sumdel += delta;
        const float4 B0 = pB[i * 4 + 0];
        const float4 B1 = pB[i * 4 + 1];
        const float4 B2 = pB[i * 4 + 2];
        const float4 B3 = pB[i * 4 + 3];
#pragma unroll
        for (int j = 0; j < DS; ++j) {
            const float a = __expf(delta * An[j]);
            h[j] = a * h[j] + u * ((j < 4) ? (&B0.x)[j] : (j < 8) ? (&B1.x)[j - 4]
                                   : (j < 12) ? (&B2.x)[j - 8] : (&B3.x)[j - 12]);
        }
    }
    const int cu = (b * DI + d) * NCHUNK + c;
    Sd[cu] = sumdel;
    float4* pH = (float4*)(H + (size_t)cu * DS);
    pH[0] = make_float4(h[0], h[1], h[2], h[3]);
    pH[1] = make_float4(h[4], h[5], h[6], h[7]);
    pH[2] = make_float4(h[8], h[9], h[10], h[11]);
    pH[3] = make_float4(h[12], h[13], h[14], h[15]);
}

// ============ S2: combine chunk summaries; P_n rebuilt as exp(An * Sd) ============
__global__ __launch_bounds__(256) void k_scan2(
    const float* __restrict__ Sd, const float* __restrict__ H,
    const float* __restrict__ A_log, float* __restrict__ H0)
{
    const int idx  = blockIdx.x * 256 + threadIdx.x;  // 24576 = (b*DI+d)*16 + n
    const int n    = idx & 15;
    const int rest = idx >> 4;                        // b*DI + d
    const int d    = rest % DI;
    const float An = -__expf(A_log[d * DS + n]);
    float Hc = 0.0f;
    for (int c = 0; c < NCHUNK; ++c) {
        const float a = __expf(An * Sd[rest * NCHUNK + c]);
        const int u = (rest * NCHUNK + c) * DS + n;
        H0[u] = Hc;
        Hc = a * Hc + H[u];
    }
}

// ============ S3: replay with h0 + fused gate; all-n in-lane, y in-register dot ============
__global__ __launch_bounds__(384) void k_scan3(
    const float* __restrict__ dt_in, const float* __restrict__ xi,
    const float* __restrict__ Bm, const float* __restrict__ Cm,
    const float* __restrict__ zs, const float* __restrict__ Dp,
    const float* __restrict__ H0, const float* __restrict__ A_log,
    const float* __restrict__ dt_w, const float* __restrict__ dt_b,
    float* __restrict__ y_out)
{
    const int tid = threadIdx.x;
    const int d   = tid % DI;
    const int cl  = tid / DI;
    const int b   = blockIdx.x >> 2;
    const int c   = ((blockIdx.x & 3) << 4) + cl;
    const int t0  = b * L_ + c * CHUNK;

    float An[DS];
#pragma unroll
    for (int j = 0; j < DS; ++j) An[j] = -__expf(A_log[d * DS + j]);
    const float dtw = dt_w[d], dtb = dt_b[d];
    const float Dpd = Dp[d];

    const int cu = (b * DI + d) * NCHUNK + c;
    float h[DS];
    {
        const float4* pH0 = (const float4*)(H0 + (size_t)cu * DS);
        const float4 a0 = pH0[0], a1 = pH0[1], a2 = pH0[2], a3 = pH0[3];
        h[0]=a0.x; h[1]=a0.y; h[2]=a0.z; h[3]=a0.w;
        h[4]=a1.x; h[5]=a1.y; h[6]=a1.z; h[7]=a1.w;
        h[8]=a2.x; h[9]=a2.y; h[10]=a2.z; h[11]=a2.w;
        h[12]=a3.x; h[13]=a3.y; h[14]=a3.z; h[15]=a3.w;
    }

    const float*  pDt = dt_in + t0;
    const float*  pX  = xi + (size_t)t0 * DI + d;
    const float*  pZ  = zs + (size_t)t0 * DI + d;
    const float4* pB  = (const float4*)(Bm + (size_t)t0 * DS);
    const float4* pC  = (const float4*)(Cm + (size_t)t0 * DS);
    float*        pY  = y_out + (size_t)t0 * DI + d;

#pragma unroll 4
    for (int i = 0; i < CHUNK; ++i) {
        const float v = fmaf(pDt[i], dtw, dtb);
        const float e = __expf(v);
        const float delta = (v > 20.0f) ? v : __logf(1.0f + e);
        const float xiv = pX[i * DI];
        const float u = delta * xiv;
        const float4 B0 = pB[i * 4 + 0];
        const float4 B1 = pB[i * 4 + 1];
        const float4 B2 = pB[i * 4 + 2];
        const float4 B3 = pB[i * 4 + 3];
        const float4 C0 = pC[i * 4 + 0];
        const float4 C1 = pC[i * 4 + 1];
        const float4 C2 = pC[i * 4 + 2];
        const float4 C3 = pC[i * 4 + 3];
        float p = 0.0f;
#pragma unroll
        for (int j = 0; j < DS; ++j) {
            const float a = __expf(delta * An[j]);
            const float Bj = (j < 4) ? (&B0.x)[j] : (j < 8) ? (&B1.x)[j - 4]
                             : (j < 12) ? (&B2.x)[j - 8] : (&B3.x)[j - 12];
            const float Cj = (j < 4) ? (&C0.x)[j] : (j < 8) ? (&C1.x)[j - 4]
                             : (j < 12) ? (&C2.x)[j - 8] : (&C3.x)[j - 12];
            h[j] = a * h[j] + u * Bj;
            p += h[j] * Cj;
        }
        pY[i * DI] = (p + xiv * Dpd) * pZ[i * DI];
    }
}

// ============ K5: two real FFTs per complex 2048-pt FFT, xfT (dm-major) out ============
__global__ __launch_bounds__(256) void k_fft(
    const float* __restrict__ x, float* __restrict__ xfT)
{
    __shared__ float re[2048], im[2048], twr[1024], twi[1024];
    const int tid = threadIdx.x;
    const int b   = blockIdx.x / (DM / 2);
    const int p   = blockIdx.x % (DM / 2);   // channel pair (2p, 2p+1)
    for (int j = tid; j < 1024; j += 256) {
        const float ang = -6.283185307179586f * (float)j * (1.0f / 2048.0f);
        float s, c;
        sincosf(ang, &s, &c);
        twr[j] = c; twi[j] = s;
    }
    for (int i = tid; i < 2048; i += 256) {
        const int r = (int)(__brev((unsigned)i) >> 21);
        const float2 v = *(const float2*)&x[(size_t)(b * L_ + i) * DM + 2 * p];
        re[r] = v.x;
        im[r] = v.y;
    }
    __syncthreads();
    for (int s = 1; s <= 11; ++s) {
        const int half  = 1 << (s - 1);
        const int tstep = 2048 >> s;
        for (int i = tid; i < 1024; i += 256) {
            const int j   = i & (half - 1);
            const int grp = i >> (s - 1);
            const int pos = (grp << s) + j;
            const float wr = twr[j * tstep], wi = twi[j * tstep];
            const float ar = re[pos + half], ai = im[pos + half];
            const float vr = wr * ar - wi * ai;
            const float vi = wr * ai + wi * ar;
            const float ur = re[pos], ui = im[pos];
            re[pos] = ur + vr;          im[pos] = ui + vi;
            re[pos + half] = ur - vr;   im[pos + half] = ui - vi;
        }
        __syncthreads();
    }
    float* row1 = xfT + (size_t)(b * DM + 2 * p) * L_;
    float* row2 = row1 + L_;
    for (int k = tid; k < 2048; k += 256) {
        const int nk = (2048 - k) & 2047;
        const float zr = re[k],  zi = im[k];
        const float qr = re[nk], qi = im[nk];
        const float e1r = zr + qr, e1i = zi - qi;
        const float e2r = zr - qr, e2i = zi + qi;
        row1[k] = 0.5f * sqrtf(e1r * e1r + e1i * e1i);
        row2[k] = 0.5f * sqrtf(e2r * e2r + e2i * e2i);
    }
}

// ============ K6: tail — SYMMETRIC inner-dim split, 2 threads/token ============
// block = 256 thr = 128 tokens x 2 halves (q = tid>>7, wave-uniform); grid = B*16 = 1024
__global__ __launch_bounds__(256) void k_tail(
    const float* __restrict__ yg, const float* __restrict__ xfT,
    const float* __restrict__ out_w,
    const float* __restrict__ ln1_g, const float* __restrict__ ln1_b,
    const float* __restrict__ w1, const float* __restrict__ b1,
    const float* __restrict__ w2, const float* __restrict__ b2,
    const float* __restrict__ lng, const float* __restrict__ lnb,
    const float* __restrict__ cnn_w, const float* __restrict__ cnn_b,
    const float* __restrict__ l1w, const float* __restrict__ l1b,
    const float* __restrict__ l2w, const float* __restrict__ l2b,
    const float* __restrict__ l3w, const float* __restrict__ l3b,
    float* __restrict__ part)
{
    __shared__ float s_ex[256][25];   // exchange buffer (25-pad: odd stride, conflict-free)
    __shared__ float sred[256];

    const int tid = threadIdx.x;
    const int b   = blockIdx.x >> 4;
    const int l0  = (blockIdx.x & 15) << 7;
    const int tok = tid & 127;
    const int q   = tid >> 7;            // 0/1, wave-uniform -> no divergence, SMEM weights
    const int pid = tid ^ 128;           // partner
    const int l   = l0 + tok;
    const int t   = b * L_ + l;

    // ---- stage A: out_proj partial over e-half + CNN partial over channel-half ----
    float yv[DM];
    *(float4*)&yv[0] = *(const float4*)&yg[(size_t)t * DI + q * DM + 0];
    *(float4*)&yv[4] = *(const float4*)&yg[(size_t)t * DI + q * DM + 4];
    *(float4*)&yv[8] = *(const float4*)&yg[(size_t)t * DI + q * DM + 8];

    float mp[DM];
#pragma unroll
    for (int j = 0; j < DM; ++j) {
        float acc = 0.0f;
#pragma unroll
        for (int e = 0; e < DM; ++e) acc += yv[e] * out_w[j * DI + q * DM + e];
        mp[j] = acc;
    }

    float xcp[DM];
#pragma unroll
    for (int o = 0; o < DM; ++o) xcp[o] = 0.0f;
#pragma unroll
    for (int ii = 0; ii < 6; ++ii) {
        const int i = q * 6 + ii;
        const float* row = xfT + (size_t)(b * DM + i) * L_;
        const float fm = (l == 0)      ? 0.0f : row[l - 1];
        const float f0 = row[l];
        const float fp = (l == L_ - 1) ? 0.0f : row[l + 1];
#pragma unroll
        for (int o = 0; o < DM; ++o) {
            const int wb = (o * DM + i) * 3;
            xcp[o] += fm * cnn_w[wb] + f0 * cnn_w[wb + 1] + fp * cnn_w[wb + 2];
        }
    }

    // ---- exchange 1: m + xc partials ----
#pragma unroll
    for (int j = 0; j < DM; ++j) { s_ex[tid][j] = mp[j]; s_ex[tid][DM + j] = xcp[j]; }
    __syncthreads();
    float m[DM], xc[DM];
#pragma unroll
    for (int j = 0; j < DM; ++j) {
        m[j]  = mp[j]  + s_ex[pid][j];
        xc[j] = xcp[j] + s_ex[pid][DM + j] + cnn_b[j];
    }

    // ---- LN1 (redundant on both halves) ----
    float mean = 0.0f;
#pragma unroll
    for (int j = 0; j < DM; ++j) mean += m[j];
    mean *= (1.0f / DM);
    float var = 0.0f;
#pragma unroll
    for (int j = 0; j < DM; ++j) { const float dv = m[j] - mean; var += dv * dv; }
    var *= (1.0f / DM);
    const float inv1 = rsqrtf(var + 1e-12f);
    float h[DM];
#pragma unroll
    for (int j = 0; j < DM; ++j) h[j] = (m[j] - mean) * inv1 * ln1_g[j] + ln1_b[j];

    // ---- FFN over e-half (24 of 48) ----
    float f2p[DM];
#pragma unroll
    for (int j = 0; j < DM; ++j) f2p[j] = 0.0f;
    const int e0 = q * 24;
#pragma unroll
    for (int e = 0; e < 24; ++e) {
        float acc = b1[e0 + e];
#pragma unroll
        for (int j = 0; j < DM; ++j) acc += h[j] * w1[(e0 + e) * DM + j];
        const float ffe = geluf(acc);
#pragma unroll
        for (int j = 0; j < DM; ++j) f2p[j] += ffe * w2[j * (4 * DM) + e0 + e];
    }

    // ---- exchange 2: f2 partials (guard sync before rewrite) ----
    __syncthreads();
#pragma unroll
    for (int j = 0; j < DM; ++j) s_ex[tid][j] = f2p[j];
    __syncthreads();
    float f2[DM];
#pragma unroll
    for (int j = 0; j < DM; ++j) f2[j] = f2p[j] + s_ex[pid][j] + b2[j] + h[j];

    // ---- LN2 (redundant) ----
    mean = 0.0f;
#pragma unroll
    for (int j = 0; j < DM; ++j) mean += f2[j];
    mean *= (1.0f / DM);
    var = 0.0f;
#pragma unroll
    for (int j = 0; j < DM; ++j) { const float dv = f2[j] - mean; var += dv * dv; }
    var *= (1.0f / DM);
    const float inv2 = rsqrtf(var + 1e-12f);
    float xm[DM];
#pragma unroll
    for (int j = 0; j < DM; ++j) xm[j] = (f2[j] - mean) * inv2 * lng[j] + lnb[j];

    // ---- head l1 partial: inner dim 24 = [xm | xc], q-half ----
    float ch[DM];
#pragma unroll
    for (int e = 0; e < DM; ++e) ch[e] = q ? xc[e] : xm[e];
    float o1p[DM];
#pragma unroll
    for (int dd = 0; dd < DM; ++dd) {
        float acc = 0.0f;
#pragma unroll
        for (int e = 0; e < DM; ++e) acc += ch[e] * l1w[dd * (2 * DM) + q * DM + e];
        o1p[dd] = acc;
    }

    // ---- exchange 3: o1 partials ----
    __syncthreads();
#pragma unroll
    for (int j = 0; j < DM; ++j) s_ex[tid][j] = o1p[j];
    __syncthreads();
    float o1[DM];
#pragma unroll
    for (int dd = 0; dd < DM; ++dd) o1[dd] = eluf(o1p[dd] + s_ex[pid][dd] + l1b[dd]);

    // ---- l2 outer-half (10 of 20) + o3 partial ----
    float o3 = 0.0f;
#pragma unroll
    for (int e = 0; e < 10; ++e) {
        const int eg = q * 10 + e;
        float acc = l2b[eg];
#pragma unroll
        for (int dd = 0; dd < DM; ++dd) acc += o1[dd] * l2w[eg * DM + dd];
        o3 += acc * l3w[eg];
    }
    if (q == 0) o3 += l3b[0];

    // ---- block reduction (256 partials = 128 tokens x 2 halves) ----
    sred[tid] = o3;
    __syncthreads();
    for (int s = 128; s > 0; s >>= 1) {
        if (tid < s) sred[tid] += sred[tid + s];
        __syncthreads();
    }
    if (tid == 0) part[blockIdx.x] = sred[0];
}

// ============ K7: final per-batch mean + sigmoid ============
__global__ void k_final(const float* __restrict__ part, float* __restrict__ out)
{
    const int b = threadIdx.x;
    if (b < B_) {
        float s = 0.0f;
        for (int i = 0; i < 16; ++i) s += part[b * 16 + i];
        s *= (1.0f / (float)L_);
        out[b] = 1.0f / (1.0f + __expf(-s));
    }
}

extern "C" void kernel_launch(void* const* d_in, const int* in_sizes, int n_in,
                              void* d_out, int out_size, void* d_ws, size_t ws_size,
                              hipStream_t stream)
{
    const float* x        = (const float*)d_in[0];
    const float* in_w     = (const float*)d_in[1];
    const float* conv_w   = (const float*)d_in[2];
    const float* conv_b   = (const float*)d_in[3];
    const float* xproj_w  = (const float*)d_in[4];
    const float* dt_w     = (const float*)d_in[5];
    const float* dt_b     = (const float*)d_in[6];
    const float* A_log    = (const float*)d_in[7];
    const float* Dp       = (const float*)d_in[8];
    const float* out_w    = (const float*)d_in[9];
    const float* ln1_g    = (const float*)d_in[10];
    const float* ln1_b    = (const float*)d_in[11];
    const float* ffn_w1   = (const float*)d_in[12];
    const float* ffn_b1   = (const float*)d_in[13];
    const float* ffn_w2   = (const float*)d_in[14];
    const float* ffn_b2   = (const float*)d_in[15];
    const float* ffn_ln_g = (const float*)d_in[16];
    const float* ffn_ln_b = (const float*)d_in[17];
    const float* cnn_w    = (const float*)d_in[18];
    const float* cnn_b    = (const float*)d_in[19];
    const float* l1w      = (const float*)d_in[20];
    const float* l1b      = (const float*)d_in[21];
    const float* l2w      = (const float*)d_in[22];
    const float* l2b      = (const float*)d_in[23];
    const float* l3w      = (const float*)d_in[24];
    const float* l3b      = (const float*)d_in[25];
    float* out = (float*)d_out;

    float* ws = (float*)d_ws;
    const size_t nTDI = (size_t)T_ * DI;
    const size_t nTDS = (size_t)T_ * DS;
    const size_t nCH  = (size_t)B_ * DI * NCHUNK;        // 98,304
    float* w_xi   = ws;
    float* w_zs   = w_xi + nTDI;
    float* w_y    = w_zs + nTDI;
    float* w_dt   = w_y + nTDI;
    float* w_Bm   = w_dt + T_;
    float* w_Cm   = w_Bm + nTDS;
    float* w_Sd   = w_Cm + nTDS;
    float* w_H    = w_Sd + nCH;
    float* w_H0   = w_H + nCH * DS;
    float* w_part = w_H0 + nCH * DS;
    float* w_xfT  = w_H;           // alias: H dead after scan2

    k_proj<<<512, 256, 0, stream>>>(x, in_w, conv_w, conv_b, xproj_w,
                                    w_xi, w_zs, w_dt, w_Bm, w_Cm);
    k_scan1<<<B_ * (NCHUNK / 16), 384, 0, stream>>>(w_dt, w_xi, w_Bm, A_log,
                                                    dt_w, dt_b, w_Sd, w_H);
    k_scan2<<<96, 256, 0, stream>>>(w_Sd, w_H, A_log, w_H0);
    k_fft<<<B_ * (DM / 2), 256, 0, stream>>>(x, w_xfT);   // overwrites H (now dead)
    k_scan3<<<B_ * (NCHUNK / 16), 384, 0, stream>>>(w_dt, w_xi, w_Bm, w_Cm, w_zs, Dp,
                                                    w_H0, A_log, dt_w, dt_b, w_y);
    k_tail<<<B_ * 16, 256, 0, stream>>>(w_y, w_xfT, out_w,
                                    ln1_g, ln1_b, ffn_w1, ffn_b1, ffn_w2, ffn_b2,
                                    ffn_ln_g, ffn_ln_b, cnn_w, cnn_b,
                                    l1w, l1b, l2w, l2b, l3w, l3b, w_part);
    k_final<<<1, 64, 0, stream>>>(w_part, out);
}

// Round 10
// 181.328 us; speedup vs baseline: 1.3806x; 1.0551x over previous
//
#include <hip/hip_runtime.h>
#include <math.h>

#define B_  64
#define L_  2048
#define DM  12
#define DI  24
#define DS  16
#define DC  4
#define DTR 1
#define T_  (B_ * L_)        // 131072 tokens
#define NCHUNK 64
#define CHUNK  32            // L_ / NCHUNK

// ---------------- ws layout (floats) — same as rounds 8/9 (passed), part grown to 2048 ----
// xi  : T*DI   3,145,728
// zs  : T*DI   3,145,728
// y   : T*DI   3,145,728
// dt  : T_       131,072
// Bm  : T*DS   2,097,152
// Cm  : T*DS   2,097,152
// Sd  : B*DI*NCHUNK          98,304
// H   : B*DI*NCHUNK*DS    1,572,864   (aliased as xf after scan2)
// H0  : B*DI*NCHUNK*DS    1,572,864
// part: 2048

__device__ __forceinline__ float siluf(float v)  { return v / (1.0f + __expf(-v)); }
__device__ __forceinline__ float geluf(float v) {
    return 0.5f * v * (1.0f + erff(v * 0.70710678118654752440f));
}
__device__ __forceinline__ float eluf(float v) { return v > 0.0f ? v : __expf(v) - 1.0f; }

// ============ K1: in_proj + depthwise causal conv + silu + x_proj; stores raw dt ============
__global__ __launch_bounds__(256) void k_proj(
    const float* __restrict__ x, const float* __restrict__ w_in,
    const float* __restrict__ conv_w, const float* __restrict__ conv_b,
    const float* __restrict__ xproj_w,
    float* __restrict__ xi_out, float* __restrict__ zs_out,
    float* __restrict__ dt_out, float* __restrict__ Bm_out,
    float* __restrict__ Cm_out)
{
    __shared__ float s_xi[256 + 3][DI + 1];
    const int tid = threadIdx.x;
    const int b   = blockIdx.x >> 3;
    const int l0  = (blockIdx.x & 7) << 8;
    const int l   = l0 + tid;
    const int t   = b * L_ + l;

    float xv[DM];
    *(float4*)&xv[0] = *(const float4*)&x[t * DM + 0];
    *(float4*)&xv[4] = *(const float4*)&x[t * DM + 4];
    *(float4*)&xv[8] = *(const float4*)&x[t * DM + 8];

#pragma unroll
    for (int e = 0; e < DI; ++e) {
        float acc = 0.0f;
#pragma unroll
        for (int d = 0; d < DM; ++d) acc += xv[d] * w_in[(DI + e) * DM + d];
        zs_out[t * DI + e] = siluf(acc);
    }
#pragma unroll
    for (int e = 0; e < DI; ++e) {
        float acc = 0.0f;
#pragma unroll
        for (int d = 0; d < DM; ++d) acc += xv[d] * w_in[e * DM + d];
        s_xi[tid + 3][e] = acc;
    }
    if (tid < 3) {
        const int lh = l0 - 3 + tid;
        if (lh < 0) {
            for (int e = 0; e < DI; ++e) s_xi[tid][e] = 0.0f;
        } else {
            const int th = b * L_ + lh;
            float xh[DM];
            for (int d = 0; d < DM; ++d) xh[d] = x[th * DM + d];
            for (int e = 0; e < DI; ++e) {
                float acc = 0.0f;
                for (int d = 0; d < DM; ++d) acc += xh[d] * w_in[e * DM + d];
                s_xi[tid][e] = acc;
            }
        }
    }
    __syncthreads();

    float xi[DI];
#pragma unroll
    for (int dch = 0; dch < DI; ++dch) {
        float acc = conv_b[dch];
#pragma unroll
        for (int k = 0; k < DC; ++k) acc += s_xi[tid + k][dch] * conv_w[dch * DC + k];
        xi[dch] = siluf(acc);
        xi_out[t * DI + dch] = xi[dch];
    }

    float dt = 0.0f;
#pragma unroll
    for (int d = 0; d < DI; ++d) dt += xi[d] * xproj_w[d];
    dt_out[t] = dt;
#pragma unroll
    for (int e = 0; e < DS; ++e) {
        float accB = 0.0f, accC = 0.0f;
#pragma unroll
        for (int d = 0; d < DI; ++d) {
            accB += xi[d] * xproj_w[(1 + e) * DI + d];
            accC += xi[d] * xproj_w[(1 + DS + e) * DI + d];
        }
        Bm_out[t * DS + e] = accB;
        Cm_out[t * DS + e] = accC;
    }
}

// ============ S1: local chunk scan — lane owns (b,c,d) with ALL 16 n-states ============
__global__ __launch_bounds__(384) void k_scan1(
    const float* __restrict__ dt_in, const float* __restrict__ xi,
    const float* __restrict__ Bm, const float* __restrict__ A_log,
    const float* __restrict__ dt_w, const float* __restrict__ dt_b,
    float* __restrict__ Sd, float* __restrict__ H)
{
    const int tid = threadIdx.x;
    const int d   = tid % DI;
    const int cl  = tid / DI;             // 0..15
    const int b   = blockIdx.x >> 2;
    const int c   = ((blockIdx.x & 3) << 4) + cl;
    const int t0  = b * L_ + c * CHUNK;

    float An[DS];
#pragma unroll
    for (int j = 0; j < DS; ++j) An[j] = -__expf(A_log[d * DS + j]);
    const float dtw = dt_w[d], dtb = dt_b[d];

    float h[DS];
#pragma unroll
    for (int j = 0; j < DS; ++j) h[j] = 0.0f;
    float sumdel = 0.0f;

    const float*  pDt = dt_in + t0;
    const float*  pX  = xi + (size_t)t0 * DI + d;
    const float4* pB  = (const float4*)(Bm + (size_t)t0 * DS);

#pragma unroll 4
    for (int i = 0; i < CHUNK; ++i) {
        const float v = fmaf(pDt[i], dtw, dtb);
        const float e = __expf(v);
        const float delta = (v > 20.0f) ? v : __logf(1.0f + e);
        const float u = delta * pX[i * DI];
        sumdel += delta;
        const float4 B0 = pB[i * 4 + 0];
        const float4 B1 = pB[i * 4 + 1];
        const float4 B2 = pB[i * 4 + 2];
        const float4 B3 = pB[i * 4 + 3];
#pragma unroll
        for (int j = 0; j < DS; ++j) {
            const float a = __expf(delta * An[j]);
            h[j] = a * h[j] + u * ((j < 4) ? (&B0.x)[j] : (j < 8) ? (&B1.x)[j - 4]
                                   : (j < 12) ? (&B2.x)[j - 8] : (&B3.x)[j - 12]);
        }
    }
    const int cu = (b * DI + d) * NCHUNK + c;
    Sd[cu] = sumdel;
    float4* pH = (float4*)(H + (size_t)cu * DS);
    pH[0] = make_float4(h[0], h[1], h[2], h[3]);
    pH[1] = make_float4(h[4], h[5], h[6], h[7]);
    pH[2] = make_float4(h[8], h[9], h[10], h[11]);
    pH[3] = make_float4(h[12], h[13], h[14], h[15]);
}

// ============ S2: combine chunk summaries; P_n rebuilt as exp(An * Sd) ============
__global__ __launch_bounds__(256) void k_scan2(
    const float* __restrict__ Sd, const float* __restrict__ H,
    const float* __restrict__ A_log, float* __restrict__ H0)
{
    const int idx  = blockIdx.x * 256 + threadIdx.x;  // 24576 = (b*DI+d)*16 + n
    const int n    = idx & 15;
    const int rest = idx >> 4;                        // b*DI + d
    const int d    = rest % DI;
    const float An = -__expf(A_log[d * DS + n]);
    float Hc = 0.0f;
    for (int c = 0; c < NCHUNK; ++c) {
        const float a = __expf(An * Sd[rest * NCHUNK + c]);
        const int u = (rest * NCHUNK + c) * DS + n;
        H0[u] = Hc;
        Hc = a * Hc + H[u];
    }
}

// ============ S3: replay with h0 + fused gate; all-n in-lane, y in-register dot ============
__global__ __launch_bounds__(384) void k_scan3(
    const float* __restrict__ dt_in, const float* __restrict__ xi,
    const float* __restrict__ Bm, const float* __restrict__ Cm,
    const float* __restrict__ zs, const float* __restrict__ Dp,
    const float* __restrict__ H0, const float* __restrict__ A_log,
    const float* __restrict__ dt_w, const float* __restrict__ dt_b,
    float* __restrict__ y_out)
{
    const int tid = threadIdx.x;
    const int d   = tid % DI;
    const int cl  = tid / DI;
    const int b   = blockIdx.x >> 2;
    const int c   = ((blockIdx.x & 3) << 4) + cl;
    const int t0  = b * L_ + c * CHUNK;

    float An[DS];
#pragma unroll
    for (int j = 0; j < DS; ++j) An[j] = -__expf(A_log[d * DS + j]);
    const float dtw = dt_w[d], dtb = dt_b[d];
    const float Dpd = Dp[d];

    const int cu = (b * DI + d) * NCHUNK + c;
    float h[DS];
    {
        const float4* pH0 = (const float4*)(H0 + (size_t)cu * DS);
        const float4 a0 = pH0[0], a1 = pH0[1], a2 = pH0[2], a3 = pH0[3];
        h[0]=a0.x; h[1]=a0.y; h[2]=a0.z; h[3]=a0.w;
        h[4]=a1.x; h[5]=a1.y; h[6]=a1.z; h[7]=a1.w;
        h[8]=a2.x; h[9]=a2.y; h[10]=a2.z; h[11]=a2.w;
        h[12]=a3.x; h[13]=a3.y; h[14]=a3.z; h[15]=a3.w;
    }

    const float*  pDt = dt_in + t0;
    const float*  pX  = xi + (size_t)t0 * DI + d;
    const float*  pZ  = zs + (size_t)t0 * DI + d;
    const float4* pB  = (const float4*)(Bm + (size_t)t0 * DS);
    const float4* pC  = (const float4*)(Cm + (size_t)t0 * DS);
    float*        pY  = y_out + (size_t)t0 * DI + d;

#pragma unroll 4
    for (int i = 0; i < CHUNK; ++i) {
        const float v = fmaf(pDt[i], dtw, dtb);
        const float e = __expf(v);
        const float delta = (v > 20.0f) ? v : __logf(1.0f + e);
        const float xiv = pX[i * DI];
        const float u = delta * xiv;
        const float4 B0 = pB[i * 4 + 0];
        const float4 B1 = pB[i * 4 + 1];
        const float4 B2 = pB[i * 4 + 2];
        const float4 B3 = pB[i * 4 + 3];
        const float4 C0 = pC[i * 4 + 0];
        const float4 C1 = pC[i * 4 + 1];
        const float4 C2 = pC[i * 4 + 2];
        const float4 C3 = pC[i * 4 + 3];
        float p = 0.0f;
#pragma unroll
        for (int j = 0; j < DS; ++j) {
            const float a = __expf(delta * An[j]);
            const float Bj = (j < 4) ? (&B0.x)[j] : (j < 8) ? (&B1.x)[j - 4]
                             : (j < 12) ? (&B2.x)[j - 8] : (&B3.x)[j - 12];
            const float Cj = (j < 4) ? (&C0.x)[j] : (j < 8) ? (&C1.x)[j - 4]
                             : (j < 12) ? (&C2.x)[j - 8] : (&C3.x)[j - 12];
            h[j] = a * h[j] + u * Bj;
            p += h[j] * Cj;
        }
        pY[i * DI] = (p + xiv * Dpd) * pZ[i * DI];
    }
}

// ============ K5: two real FFTs per complex 2048-pt FFT, xfT (dm-major) out ============
__global__ __launch_bounds__(256) void k_fft(
    const float* __restrict__ x, float* __restrict__ xfT)
{
    __shared__ float re[2048], im[2048], twr[1024], twi[1024];
    const int tid = threadIdx.x;
    const int b   = blockIdx.x / (DM / 2);
    const int p   = blockIdx.x % (DM / 2);   // channel pair (2p, 2p+1)
    for (int j = tid; j < 1024; j += 256) {
        const float ang = -6.283185307179586f * (float)j * (1.0f / 2048.0f);
        float s, c;
        sincosf(ang, &s, &c);
        twr[j] = c; twi[j] = s;
    }
    for (int i = tid; i < 2048; i += 256) {
        const int r = (int)(__brev((unsigned)i) >> 21);
        const float2 v = *(const float2*)&x[(size_t)(b * L_ + i) * DM + 2 * p];
        re[r] = v.x;
        im[r] = v.y;
    }
    __syncthreads();
    for (int s = 1; s <= 11; ++s) {
        const int half  = 1 << (s - 1);
        const int tstep = 2048 >> s;
        for (int i = tid; i < 1024; i += 256) {
            const int j   = i & (half - 1);
            const int grp = i >> (s - 1);
            const int pos = (grp << s) + j;
            const float wr = twr[j * tstep], wi = twi[j * tstep];
            const float ar = re[pos + half], ai = im[pos + half];
            const float vr = wr * ar - wi * ai;
            const float vi = wr * ai + wi * ar;
            const float ur = re[pos], ui = im[pos];
            re[pos] = ur + vr;          im[pos] = ui + vi;
            re[pos + half] = ur - vr;   im[pos + half] = ui - vi;
        }
        __syncthreads();
    }
    float* row1 = xfT + (size_t)(b * DM + 2 * p) * L_;
    float* row2 = row1 + L_;
    for (int k = tid; k < 2048; k += 256) {
        const int nk = (2048 - k) & 2047;
        const float zr = re[k],  zi = im[k];
        const float qr = re[nk], qi = im[nk];
        const float e1r = zr + qr, e1i = zi - qi;
        const float e2r = zr - qr, e2i = zi + qi;
        row1[k] = 0.5f * sqrtf(e1r * e1r + e1i * e1i);
        row2[k] = 0.5f * sqrtf(e2r * e2r + e2i * e2i);
    }
}

// ============ K6: tail — STAGE-PARALLEL: block = 64 tokens, thread = (tok, out-elem) ========
// elem = e*64 + tok  ->  lanes 0..63 share e  ->  weight loads are wave-uniform (SGPR)
// grid = B*32 = 2048 blocks; LDS ~36.6 KB -> 4 blocks/CU; small per-thread state
__global__ __launch_bounds__(256) void k_tail(
    const float* __restrict__ yg, const float* __restrict__ xfT,
    const float* __restrict__ out_w,
    const float* __restrict__ ln1_g, const float* __restrict__ ln1_b,
    const float* __restrict__ w1, const float* __restrict__ b1,
    const float* __restrict__ w2, const float* __restrict__ b2,
    const float* __restrict__ lng, const float* __restrict__ lnb,
    const float* __restrict__ cnn_w, const float* __restrict__ cnn_b,
    const float* __restrict__ l1w, const float* __restrict__ l1b,
    const float* __restrict__ l2w, const float* __restrict__ l2b,
    const float* __restrict__ l3w,
    float* __restrict__ part)
{
    __shared__ float sY[64][25];     // staged y
    __shared__ float sM[64][13];     // m, reused as f2
    __shared__ float sH[64][13];     // LN1 out
    __shared__ float sFF[64][49];    // gelu outputs
    __shared__ float sXM[64][13];    // LN2 out
    __shared__ float sXC[64][13];    // CNN out
    __shared__ float sO1[64][13];    // head l1 out
    __shared__ float sred[256];

    const int tid = threadIdx.x;
    const int b   = blockIdx.x >> 5;
    const int l0  = (blockIdx.x & 31) << 6;
    const int tok = tid & 63;
    const int sub = tid >> 6;            // 0..3, wave-uniform
    const int l   = l0 + tok;

    // ---- stage y (coalesced) ----
    {
        const float* gy = yg + ((size_t)b * L_ + l0) * DI;
#pragma unroll
        for (int k = 0; k < 6; ++k) {
            const int j = k * 256 + tid;
            sY[j / DI][j % DI] = gy[j];
        }
    }
    __syncthreads();

    // ---- out_proj (768 elems, 3/thread) + CNN (768 elems, 3/thread) ----
    {
        float yr[DI];
#pragma unroll
        for (int i = 0; i < DI; ++i) yr[i] = sY[tok][i];
#pragma unroll
        for (int k = 0; k < 3; ++k) {
            const int e = k * 4 + sub;
            float acc = 0.0f;
#pragma unroll
            for (int i = 0; i < DI; ++i) acc += yr[i] * out_w[e * DI + i];
            sM[tok][e] = acc;
        }
    }
    {
        float fm[DM], f0[DM], fp[DM];
#pragma unroll
        for (int i = 0; i < DM; ++i) {
            const float* row = xfT + (size_t)(b * DM + i) * L_;
            fm[i] = (l == 0)      ? 0.0f : row[l - 1];
            f0[i] = row[l];
            fp[i] = (l == L_ - 1) ? 0.0f : row[l + 1];
        }
#pragma unroll
        for (int k = 0; k < 3; ++k) {
            const int o = k * 4 + sub;
            float acc = cnn_b[o];
#pragma unroll
            for (int i = 0; i < DM; ++i) {
                const int wb = (o * DM + i) * 3;
                acc += fm[i] * cnn_w[wb] + f0[i] * cnn_w[wb + 1] + fp[i] * cnn_w[wb + 2];
            }
            sXC[tok][o] = acc;
        }
    }
    __syncthreads();

    // ---- LN1 (64 threads, 1/token) ----
    if (tid < 64) {
        float m[DM];
        float mean = 0.0f;
#pragma unroll
        for (int j = 0; j < DM; ++j) { m[j] = sM[tid][j]; mean += m[j]; }
        mean *= (1.0f / DM);
        float var = 0.0f;
#pragma unroll
        for (int j = 0; j < DM; ++j) { const float dv = m[j] - mean; var += dv * dv; }
        var *= (1.0f / DM);
        const float inv = rsqrtf(var + 1e-12f);
#pragma unroll
        for (int j = 0; j < DM; ++j) sH[tid][j] = (m[j] - mean) * inv * ln1_g[j] + ln1_b[j];
    }
    __syncthreads();

    // ---- FFN1 (3072 elems, 12/thread) ----
    {
        float hr[DM];
#pragma unroll
        for (int j = 0; j < DM; ++j) hr[j] = sH[tok][j];
#pragma unroll
        for (int k = 0; k < 12; ++k) {
            const int e = k * 4 + sub;
            float acc = b1[e];
#pragma unroll
            for (int j = 0; j < DM; ++j) acc += hr[j] * w1[e * DM + j];
            sFF[tok][e] = geluf(acc);
        }
    }
    __syncthreads();

    // ---- FFN2 + residual -> f2 (768 elems, 3/thread), reuse sM ----
#pragma unroll
    for (int k = 0; k < 3; ++k) {
        const int j = k * 4 + sub;
        float acc = b2[j] + sH[tok][j];
#pragma unroll
        for (int e = 0; e < 4 * DM; ++e) acc += sFF[tok][e] * w2[j * (4 * DM) + e];
        sM[tok][j] = acc;
    }
    __syncthreads();

    // ---- LN2 (64 threads) -> sXM ----
    if (tid < 64) {
        float m[DM];
        float mean = 0.0f;
#pragma unroll
        for (int j = 0; j < DM; ++j) { m[j] = sM[tid][j]; mean += m[j]; }
        mean *= (1.0f / DM);
        float var = 0.0f;
#pragma unroll
        for (int j = 0; j < DM; ++j) { const float dv = m[j] - mean; var += dv * dv; }
        var *= (1.0f / DM);
        const float inv = rsqrtf(var + 1e-12f);
#pragma unroll
        for (int j = 0; j < DM; ++j) sXM[tid][j] = (m[j] - mean) * inv * lng[j] + lnb[j];
    }
    __syncthreads();

    // ---- head l1 (768 elems, 3/thread) ----
    {
        float xmr[DM], xcr[DM];
#pragma unroll
        for (int e = 0; e < DM; ++e) { xmr[e] = sXM[tok][e]; xcr[e] = sXC[tok][e]; }
#pragma unroll
        for (int k = 0; k < 3; ++k) {
            const int d = k * 4 + sub;
            float acc = l1b[d];
#pragma unroll
            for (int e = 0; e < DM; ++e)
                acc += xmr[e] * l1w[d * (2 * DM) + e] + xcr[e] * l1w[d * (2 * DM) + DM + e];
            sO1[tok][d] = eluf(acc);
        }
    }
    __syncthreads();

    // ---- l2 x l3 (1280 elems, 5/thread) + block reduce; l3b added in k_final ----
    float p = 0.0f;
    {
        float o1r[DM];
#pragma unroll
        for (int d = 0; d < DM; ++d) o1r[d] = sO1[tok][d];
#pragma unroll
        for (int k = 0; k < 5; ++k) {
            const int e = k * 4 + sub;
            float acc = l2b[e];
#pragma unroll
            for (int d = 0; d < DM; ++d) acc += o1r[d] * l2w[e * DM + d];
            p += acc * l3w[e];
        }
    }
    sred[tid] = p;
    __syncthreads();
    for (int s = 128; s > 0; s >>= 1) {
        if (tid < s) sred[tid] += sred[tid + s];
        __syncthreads();
    }
    if (tid == 0) part[blockIdx.x] = sred[0];
}

// ============ K7: final per-batch mean + l3b + sigmoid ============
__global__ void k_final(const float* __restrict__ part, const float* __restrict__ l3b,
                        float* __restrict__ out)
{
    const int b = threadIdx.x;
    if (b < B_) {
        float s = 0.0f;
        for (int i = 0; i < 32; ++i) s += part[b * 32 + i];
        s = s * (1.0f / (float)L_) + l3b[0];
        out[b] = 1.0f / (1.0f + __expf(-s));
    }
}

extern "C" void kernel_launch(void* const* d_in, const int* in_sizes, int n_in,
                              void* d_out, int out_size, void* d_ws, size_t ws_size,
                              hipStream_t stream)
{
    const float* x        = (const float*)d_in[0];
    const float* in_w     = (const float*)d_in[1];
    const float* conv_w   = (const float*)d_in[2];
    const float* conv_b   = (const float*)d_in[3];
    const float* xproj_w  = (const float*)d_in[4];
    const float* dt_w     = (const float*)d_in[5];
    const float* dt_b     = (const float*)d_in[6];
    const float* A_log    = (const float*)d_in[7];
    const float* Dp       = (const float*)d_in[8];
    const float* out_w    = (const float*)d_in[9];
    const float* ln1_g    = (const float*)d_in[10];
    const float* ln1_b    = (const float*)d_in[11];
    const float* ffn_w1   = (const float*)d_in[12];
    const float* ffn_b1   = (const float*)d_in[13];
    const float* ffn_w2   = (const float*)d_in[14];
    const float* ffn_b2   = (const float*)d_in[15];
    const float* ffn_ln_g = (const float*)d_in[16];
    const float* ffn_ln_b = (const float*)d_in[17];
    const float* cnn_w    = (const float*)d_in[18];
    const float* cnn_b    = (const float*)d_in[19];
    const float* l1w      = (const float*)d_in[20];
    const float* l1b      = (const float*)d_in[21];
    const float* l2w      = (const float*)d_in[22];
    const float* l2b      = (const float*)d_in[23];
    const float* l3w      = (const float*)d_in[24];
    const float* l3b      = (const float*)d_in[25];
    float* out = (float*)d_out;

    float* ws = (float*)d_ws;
    const size_t nTDI = (size_t)T_ * DI;
    const size_t nTDS = (size_t)T_ * DS;
    const size_t nCH  = (size_t)B_ * DI * NCHUNK;        // 98,304
    float* w_xi   = ws;
    float* w_zs   = w_xi + nTDI;
    float* w_y    = w_zs + nTDI;
    float* w_dt   = w_y + nTDI;
    float* w_Bm   = w_dt + T_;
    float* w_Cm   = w_Bm + nTDS;
    float* w_Sd   = w_Cm + nTDS;
    float* w_H    = w_Sd + nCH;
    float* w_H0   = w_H + nCH * DS;
    float* w_part = w_H0 + nCH * DS;
    float* w_xfT  = w_H;           // alias: H dead after scan2

    k_proj<<<512, 256, 0, stream>>>(x, in_w, conv_w, conv_b, xproj_w,
                                    w_xi, w_zs, w_dt, w_Bm, w_Cm);
    k_scan1<<<B_ * (NCHUNK / 16), 384, 0, stream>>>(w_dt, w_xi, w_Bm, A_log,
                                                    dt_w, dt_b, w_Sd, w_H);
    k_scan2<<<96, 256, 0, stream>>>(w_Sd, w_H, A_log, w_H0);
    k_fft<<<B_ * (DM / 2), 256, 0, stream>>>(x, w_xfT);   // overwrites H (now dead)
    k_scan3<<<B_ * (NCHUNK / 16), 384, 0, stream>>>(w_dt, w_xi, w_Bm, w_Cm, w_zs, Dp,
                                                    w_H0, A_log, dt_w, dt_b, w_y);
    k_tail<<<B_ * 32, 256, 0, stream>>>(w_y, w_xfT, out_w,
                                    ln1_g, ln1_b, ffn_w1, ffn_b1, ffn_w2, ffn_b2,
                                    ffn_ln_g, ffn_ln_b, cnn_w, cnn_b,
                                    l1w, l1b, l2w, l2b, l3w, w_part);
    k_final<<<1, 64, 0, stream>>>(w_part, l3b, out);
}